// Round 1
// baseline (1763.929 us; speedup 1.0000x reference)
//
#include <hip/hip_runtime.h>
#include <math.h>

namespace {

constexpr int Bc  = 2;
constexpr int Sc  = 2048;
constexpr int Dc  = 1024;
constexpr int NHc = 16;
constexpr int HDc = 64;
constexpr int Mc  = Bc * Sc;   // 4096 rows total

// ---------------------------------------------------------------------------
// C[M,N] = A[M,K] @ W[N,K]^T  (+ bias[N] if BIAS)
// 64x64 tile, BK=16, 256 threads, 4x4 micro-tile per thread.
// ---------------------------------------------------------------------------
template<bool BIAS>
__global__ __launch_bounds__(256)
void gemm_xt(const float* __restrict__ A, const float* __restrict__ W,
             const float* __restrict__ bias, float* __restrict__ C,
             int N, int K)
{
    // Transposed LDS tiles: As[k][m]. Pad 68 keeps 16B alignment for float4
    // reads (68*4 = 272 = 17*16) and gives only benign 2-way aliasing.
    __shared__ __align__(16) float As[16][68];
    __shared__ __align__(16) float Ws[16][68];

    const int tid  = threadIdx.x;
    const int tx   = tid & 15;          // micro-tile col group
    const int ty   = tid >> 4;          // micro-tile row group
    const int row0 = blockIdx.y * 64;
    const int col0 = blockIdx.x * 64;

    // load assignment: thread -> (row lr, k-quad lk), float4 per iteration
    const int lr = tid >> 2;            // 0..63
    const int lk = (tid & 3) << 2;      // 0,4,8,12

    const float* Ap = A + (size_t)(row0 + lr) * K + lk;
    const float* Wp = W + (size_t)(col0 + lr) * K + lk;

    float acc[4][4] = {};

    for (int kt = 0; kt < K; kt += 16) {
        const float4 av = *(const float4*)(Ap + kt);
        const float4 wv = *(const float4*)(Wp + kt);
        __syncthreads();                       // protect previous tile reads
        As[lk + 0][lr] = av.x; As[lk + 1][lr] = av.y;
        As[lk + 2][lr] = av.z; As[lk + 3][lr] = av.w;
        Ws[lk + 0][lr] = wv.x; Ws[lk + 1][lr] = wv.y;
        Ws[lk + 2][lr] = wv.z; Ws[lk + 3][lr] = wv.w;
        __syncthreads();

        #pragma unroll
        for (int k = 0; k < 16; ++k) {
            const float4 a = *(const float4*)&As[k][ty << 2];
            const float4 b = *(const float4*)&Ws[k][tx << 2];
            acc[0][0] += a.x * b.x; acc[0][1] += a.x * b.y;
            acc[0][2] += a.x * b.z; acc[0][3] += a.x * b.w;
            acc[1][0] += a.y * b.x; acc[1][1] += a.y * b.y;
            acc[1][2] += a.y * b.z; acc[1][3] += a.y * b.w;
            acc[2][0] += a.z * b.x; acc[2][1] += a.z * b.y;
            acc[2][2] += a.z * b.z; acc[2][3] += a.z * b.w;
            acc[3][0] += a.w * b.x; acc[3][1] += a.w * b.y;
            acc[3][2] += a.w * b.z; acc[3][3] += a.w * b.w;
        }
    }

    const int cc = col0 + (tx << 2);
    float4 badd = make_float4(0.f, 0.f, 0.f, 0.f);
    if (BIAS) {
        badd = *(const float4*)(bias + cc);
    }
    #pragma unroll
    for (int i = 0; i < 4; ++i) {
        float4 o;
        o.x = acc[i][0] + badd.x;
        o.y = acc[i][1] + badd.y;
        o.z = acc[i][2] + badd.z;
        o.w = acc[i][3] + badd.w;
        *(float4*)(C + (size_t)(row0 + (ty << 2) + i) * N + cc) = o;
    }
}

// ---------------------------------------------------------------------------
// Flash-style causal attention, fp32.
// grid = (S/4, NH, B); block = 256 (4 waves). Wave w handles query qb*4+w.
// Lane j owns score j of the 64-wide K tile; lane d owns output dim d.
// K tile staged transposed (Kts[dim][k]) so the score inner loop is
// conflict-free; V tile row-major (PV inner loop conflict-free). Pad 65.
// ---------------------------------------------------------------------------
__global__ __launch_bounds__(256)
void attn_fwd(const float* __restrict__ Qg, const float* __restrict__ Kg,
              const float* __restrict__ Vg, float* __restrict__ Og)
{
    __shared__ float Kts[64][65];   // [dim][k]
    __shared__ float Vs[64][65];    // [k][dim]
    __shared__ float qs[4][64];
    __shared__ float ps[4][64];

    const int tid  = threadIdx.x;
    const int lane = tid & 63;
    const int wave = tid >> 6;
    const int qb   = blockIdx.x;
    const int h    = blockIdx.y;
    const int b    = blockIdx.z;
    const int q_idx = qb * 4 + wave;
    const float scale = 0.125f;     // 1/sqrt(64)

    // stage this wave's q row (lane d holds q[d]; LDS row for broadcast)
    qs[wave][lane] = Qg[((size_t)(b * Sc + q_idx)) * Dc + h * HDc + lane];

    float m = -INFINITY, l = 0.f, acc = 0.f;

    const int ktiles = (qb >> 4) + 1;   // ceil((q_max+1)/64)
    for (int kt = 0; kt < ktiles; ++kt) {
        const int k0 = kt * 64;
        __syncthreads();   // previous tile fully consumed
        // cooperative staging: 64 rows x 64 floats, 4 float4 per thread
        #pragma unroll
        for (int it = 0; it < 4; ++it) {
            const int g  = tid + it * 256;
            const int r  = g >> 4;
            const int c4 = (g & 15) << 2;
            const size_t src = ((size_t)(b * Sc + k0 + r)) * Dc + h * HDc + c4;
            const float4 kv = *(const float4*)(Kg + src);
            const float4 vv = *(const float4*)(Vg + src);
            Kts[c4 + 0][r] = kv.x; Kts[c4 + 1][r] = kv.y;
            Kts[c4 + 2][r] = kv.z; Kts[c4 + 3][r] = kv.w;
            Vs[r][c4 + 0] = vv.x; Vs[r][c4 + 1] = vv.y;
            Vs[r][c4 + 2] = vv.z; Vs[r][c4 + 3] = vv.w;
        }
        __syncthreads();

        // scores: lane j computes q . K[k0+j]
        float s = 0.f;
        #pragma unroll 8
        for (int i = 0; i < 64; ++i)
            s += qs[wave][i] * Kts[i][lane];
        s = (k0 + lane <= q_idx) ? s * scale : -INFINITY;

        // online softmax update (64-lane reductions)
        float tm = s;
        #pragma unroll
        for (int off = 32; off; off >>= 1)
            tm = fmaxf(tm, __shfl_xor(tm, off));
        const float mn = fmaxf(m, tm);
        const float p  = __expf(s - mn);       // masked lanes -> 0
        const float c  = __expf(m - mn);       // first tile: 0
        float psum = p;
        #pragma unroll
        for (int off = 32; off; off >>= 1)
            psum += __shfl_xor(psum, off);
        l = l * c + psum;
        m = mn;

        ps[wave][lane] = p;                    // same-wave LDS handoff
        float a = 0.f;
        #pragma unroll 8
        for (int j = 0; j < 64; ++j)
            a += ps[wave][j] * Vs[j][lane];
        acc = acc * c + a;
    }

    Og[((size_t)(b * Sc + q_idx)) * Dc + h * HDc + lane] = acc / l;
}

} // namespace

// ---------------------------------------------------------------------------
extern "C" void kernel_launch(void* const* d_in, const int* in_sizes, int n_in,
                              void* d_out, int out_size, void* d_ws, size_t ws_size,
                              hipStream_t stream)
{
    const float* x  = (const float*)d_in[0];
    const float* wq = (const float*)d_in[1];
    const float* wk = (const float*)d_in[2];
    const float* wv = (const float*)d_in[3];
    const float* wo = (const float*)d_in[4];
    const float* wb = (const float*)d_in[5];
    float* out = (float*)d_out;

    float* ws = (float*)d_ws;
    const size_t MD = (size_t)Mc * Dc;     // 4M floats
    float* Q  = ws;
    float* K  = ws + MD;
    float* V  = ws + 2 * MD;
    float* AO = ws + 3 * MD;

    const dim3 gg(Dc / 64, Mc / 64);       // (16, 64)
    gemm_xt<false><<<gg, 256, 0, stream>>>(x, wq, nullptr, Q, Dc, Dc);
    gemm_xt<false><<<gg, 256, 0, stream>>>(x, wk, nullptr, K, Dc, Dc);
    gemm_xt<false><<<gg, 256, 0, stream>>>(x, wv, nullptr, V, Dc, Dc);

    attn_fwd<<<dim3(Sc / 4, NHc, Bc), 256, 0, stream>>>(Q, K, V, AO);

    gemm_xt<true><<<gg, 256, 0, stream>>>(AO, wo, wb, out, Dc, Dc);
}

// Round 2
// 387.626 us; speedup vs baseline: 4.5506x; 4.5506x over previous
//
#include <hip/hip_runtime.h>
#include <math.h>
#include <stdint.h>

namespace {

typedef unsigned short u16;
typedef short    bf16x8 __attribute__((ext_vector_type(8)));   // 8 bf16 (4 VGPR)
typedef float    f32x4  __attribute__((ext_vector_type(4)));
typedef u16      u16x4  __attribute__((ext_vector_type(4)));
typedef u16      u16x8  __attribute__((ext_vector_type(8)));

constexpr int SEQ = 2048;
constexpr int DIM = 1024;
constexpr int NHE = 16;
constexpr int HDM = 64;
constexpr int MROWS = 2 * SEQ;     // 4096

__device__ __forceinline__ u16 f2bf(float f) {   // RNE fp32 -> bf16
    uint32_t u = __float_as_uint(f);
    u += 0x7fffu + ((u >> 16) & 1u);
    return (u16)(u >> 16);
}

#define MFMA16(a, b, c) __builtin_amdgcn_mfma_f32_16x16x32_bf16((a), (b), (c), 0, 0, 0)

// ---------------------------------------------------------------------------
// fp32 -> bf16 conversion for x and the 4 weight matrices.
// ---------------------------------------------------------------------------
__global__ __launch_bounds__(256)
void convert_bf16(const float* __restrict__ x,  const float* __restrict__ wq,
                  const float* __restrict__ wk, const float* __restrict__ wv,
                  const float* __restrict__ wo, u16* __restrict__ ws)
{
    const int id = blockIdx.y;
    const float* src;  u16* dst;  int n;
    if      (id == 0) { src = x;  dst = ws;                        n = 1 << 22; }
    else if (id == 1) { src = wq; dst = ws + ((size_t)4 << 20);    n = 1 << 20; }
    else if (id == 2) { src = wk; dst = ws + ((size_t)5 << 20);    n = 1 << 20; }
    else if (id == 3) { src = wv; dst = ws + ((size_t)6 << 20);    n = 1 << 20; }
    else              { src = wo; dst = ws + ((size_t)7 << 20);    n = 1 << 20; }

    const int stride = gridDim.x * 256 * 8;
    for (int i = (blockIdx.x * 256 + threadIdx.x) * 8; i < n; i += stride) {
        const float4 a = *(const float4*)(src + i);
        const float4 b = *(const float4*)(src + i + 4);
        u16x8 o;
        o[0] = f2bf(a.x); o[1] = f2bf(a.y); o[2] = f2bf(a.z); o[3] = f2bf(a.w);
        o[4] = f2bf(b.x); o[5] = f2bf(b.y); o[6] = f2bf(b.z); o[7] = f2bf(b.w);
        *(u16x8*)(dst + i) = o;
    }
}

// ---------------------------------------------------------------------------
// Shared bf16 GEMM core: C[128x128] tile of A[M,1024] @ W[1024,1024]^T.
// 256 threads = 4 waves (2x2), wave tile 64x64 = 4x4 fragments of 16x16.
// Reg-staged LDS, row stride 40 elems (80 B) to spread b128 read banks.
// ---------------------------------------------------------------------------
constexpr int LDT = 40;

__device__ __forceinline__ void gemm_core(
    const u16* __restrict__ A, const u16* __restrict__ W,
    int row0, int col0, u16* As, u16* Bs, f32x4 acc[4][4])
{
    const int tid  = threadIdx.x;
    const int lane = tid & 63;
    const int wave = tid >> 6;
    const int wm = wave >> 1, wn = wave & 1;
    const int col = lane & 15, g = lane >> 4;

    // staging assignment: chunk c covers LDS row c>>2, k-oct (c&3)*8
    const int c0 = tid, c1 = tid + 256;
    const int r0 = c0 >> 2, k0 = (c0 & 3) << 3;
    const int r1 = c1 >> 2, k1 = (c1 & 3) << 3;

    const u16* A0 = A + (size_t)(row0 + r0) * DIM + k0;
    const u16* A1 = A + (size_t)(row0 + r1) * DIM + k1;
    const u16* W0 = W + (size_t)(col0 + r0) * DIM + k0;
    const u16* W1 = W + (size_t)(col0 + r1) * DIM + k1;

    u16* sA0 = As + r0 * LDT + k0;  u16* sA1 = As + r1 * LDT + k1;
    u16* sB0 = Bs + r0 * LDT + k0;  u16* sB1 = Bs + r1 * LDT + k1;

    for (int kt = 0; kt < DIM; kt += 32) {
        const bf16x8 av0 = *(const bf16x8*)(A0 + kt);
        const bf16x8 av1 = *(const bf16x8*)(A1 + kt);
        const bf16x8 wv0 = *(const bf16x8*)(W0 + kt);
        const bf16x8 wv1 = *(const bf16x8*)(W1 + kt);
        __syncthreads();                 // previous tile fully consumed
        *(bf16x8*)sA0 = av0;  *(bf16x8*)sA1 = av1;
        *(bf16x8*)sB0 = wv0;  *(bf16x8*)sB1 = wv1;
        __syncthreads();

        bf16x8 af[4], bfr[4];
        #pragma unroll
        for (int i = 0; i < 4; ++i)
            af[i] = *(const bf16x8*)(As + (wm * 64 + i * 16 + col) * LDT + g * 8);
        #pragma unroll
        for (int i = 0; i < 4; ++i)
            bfr[i] = *(const bf16x8*)(Bs + (wn * 64 + i * 16 + col) * LDT + g * 8);
        #pragma unroll
        for (int i = 0; i < 4; ++i)
            #pragma unroll
            for (int j = 0; j < 4; ++j)
                acc[i][j] = MFMA16(af[i], bfr[j], acc[i][j]);
    }
}

// ---------------------------------------------------------------------------
// QKV projections. z=0 -> Q, z=1 -> K (row-major [4096][1024] bf16);
// z=2 -> V written transposed per head: Vt[(b*16+h)*64 + d][s] (bf16).
// ---------------------------------------------------------------------------
__global__ __launch_bounds__(256)
void gemm_qkv(const u16* __restrict__ xb,  const u16* __restrict__ wqb,
              const u16* __restrict__ wkb, const u16* __restrict__ wvb,
              u16* __restrict__ Qb, u16* __restrict__ Kb, u16* __restrict__ Vtb)
{
    __shared__ u16 As[128 * LDT];
    __shared__ u16 Bs[128 * LDT];

    const int z = blockIdx.z;
    const u16* W = (z == 0) ? wqb : (z == 1) ? wkb : wvb;
    const int row0 = blockIdx.y * 128, col0 = blockIdx.x * 128;

    f32x4 acc[4][4];
    const f32x4 zero = {0.f, 0.f, 0.f, 0.f};
    #pragma unroll
    for (int i = 0; i < 4; ++i)
        #pragma unroll
        for (int j = 0; j < 4; ++j) acc[i][j] = zero;

    gemm_core(xb, W, row0, col0, As, Bs, acc);

    const int lane = threadIdx.x & 63, wave = threadIdx.x >> 6;
    const int wm = wave >> 1, wn = wave & 1;
    const int col = lane & 15, g = lane >> 4;

    if (z < 2) {
        u16* O = z ? Kb : Qb;
        #pragma unroll
        for (int i = 0; i < 4; ++i) {
            const int r_ = row0 + wm * 64 + i * 16 + g * 4;
            #pragma unroll
            for (int j = 0; j < 4; ++j) {
                const int c_ = col0 + wn * 64 + j * 16 + col;
                #pragma unroll
                for (int r = 0; r < 4; ++r)
                    O[(size_t)(r_ + r) * DIM + c_] = f2bf(acc[i][j][r]);
            }
        }
    } else {
        #pragma unroll
        for (int i = 0; i < 4; ++i) {
            const int r_ = row0 + wm * 64 + i * 16 + g * 4;   // 4-aligned
            const int b = r_ >> 11, s = r_ & 2047;
            #pragma unroll
            for (int j = 0; j < 4; ++j) {
                const int c_ = col0 + wn * 64 + j * 16 + col;
                const int h = c_ >> 6, d = c_ & 63;
                u16x4 pk;
                #pragma unroll
                for (int r = 0; r < 4; ++r) pk[r] = f2bf(acc[i][j][r]);
                *(u16x4*)(Vtb + (((size_t)(b * NHE + h) * HDM + d) << 11) + s) = pk;
            }
        }
    }
}

// ---------------------------------------------------------------------------
// Output projection: out = AO @ wo^T + bias (fp32 out).
// ---------------------------------------------------------------------------
__global__ __launch_bounds__(256)
void gemm_out(const u16* __restrict__ AOb, const u16* __restrict__ wob,
              const float* __restrict__ bias, float* __restrict__ out)
{
    __shared__ u16 As[128 * LDT];
    __shared__ u16 Bs[128 * LDT];

    const int row0 = blockIdx.y * 128, col0 = blockIdx.x * 128;
    f32x4 acc[4][4];
    const f32x4 zero = {0.f, 0.f, 0.f, 0.f};
    #pragma unroll
    for (int i = 0; i < 4; ++i)
        #pragma unroll
        for (int j = 0; j < 4; ++j) acc[i][j] = zero;

    gemm_core(AOb, wob, row0, col0, As, Bs, acc);

    const int lane = threadIdx.x & 63, wave = threadIdx.x >> 6;
    const int wm = wave >> 1, wn = wave & 1;
    const int col = lane & 15, g = lane >> 4;

    #pragma unroll
    for (int i = 0; i < 4; ++i) {
        const int r_ = row0 + wm * 64 + i * 16 + g * 4;
        #pragma unroll
        for (int j = 0; j < 4; ++j) {
            const int c_ = col0 + wn * 64 + j * 16 + col;
            const float bv = bias[c_];
            #pragma unroll
            for (int r = 0; r < 4; ++r)
                out[(size_t)(r_ + r) * DIM + c_] = acc[i][j][r] + bv;
        }
    }
}

// ---------------------------------------------------------------------------
// MFMA flash attention (causal). grid=(32,16,2), 256 thr = 4 waves.
// Wave w owns q rows [qt*64+w*16, +16). Swapped QK^T: S^T = mfma(K, Q)
// so lane (col=l&15) owns q-column q0+col; softmax reduce = in-lane + xor16/32.
// K read directly from global (L2-resident); V read from pre-transposed Vt.
// P round-trips through wave-private LDS (no __syncthreads anywhere).
// ---------------------------------------------------------------------------
__global__ __launch_bounds__(256)
void attn_mfma(const u16* __restrict__ Qb, const u16* __restrict__ Kb,
               const u16* __restrict__ Vtb, u16* __restrict__ AOb)
{
    __shared__ u16 P[4][16][80];        // [wave][q][key 0..63, pad 80]

    const int tid = threadIdx.x, lane = tid & 63, wave = tid >> 6;
    const int col = lane & 15, g = lane >> 4;
    const int qt = blockIdx.x, h = blockIdx.y, b = blockIdx.z;
    const int q0 = qt * 64 + wave * 16;
    const int qloc = wave * 16 + col;   // q within the 64-wide tile
    const float scale = 0.125f;         // 1/sqrt(64)

    // Q B-fragments (hoisted): lane holds Q[q0+col][d-set]
    const u16* Qrow = Qb + (size_t)(b * SEQ + q0 + col) * DIM + h * HDM;
    const bf16x8 qf0 = *(const bf16x8*)(Qrow + g * 8);
    const bf16x8 qf1 = *(const bf16x8*)(Qrow + 32 + g * 8);

    float m = -INFINITY, l = 0.f;
    f32x4 o[4];
    const f32x4 zero = {0.f, 0.f, 0.f, 0.f};
    #pragma unroll
    for (int i = 0; i < 4; ++i) o[i] = zero;

    const u16* Kbase = Kb + (size_t)(b * SEQ) * DIM + h * HDM;
    const u16* Vbase = Vtb + (((size_t)(b * NHE + h) * HDM) << 11);

    for (int kt = 0; kt <= qt; ++kt) {
        const int k0 = kt * 64;

        // S^T tile: 4 key-fragments x (2 mfma over d)
        f32x4 st[4];
        #pragma unroll
        for (int kf = 0; kf < 4; ++kf) {
            const u16* Krow = Kbase + (size_t)(k0 + kf * 16 + col) * DIM;
            const bf16x8 ka0 = *(const bf16x8*)(Krow + g * 8);
            const bf16x8 ka1 = *(const bf16x8*)(Krow + 32 + g * 8);
            f32x4 z = zero;
            z = MFMA16(ka0, qf0, z);
            z = MFMA16(ka1, qf1, z);
            st[kf] = z;
        }

        float sv[16];
        #pragma unroll
        for (int kf = 0; kf < 4; ++kf)
            #pragma unroll
            for (int r = 0; r < 4; ++r)
                sv[kf * 4 + r] = st[kf][r] * scale;

        if (kt == qt) {                   // diagonal tile: causal mask
            #pragma unroll
            for (int kf = 0; kf < 4; ++kf)
                #pragma unroll
                for (int r = 0; r < 4; ++r)
                    if (kf * 16 + g * 4 + r > qloc) sv[kf * 4 + r] = -INFINITY;
        }

        float mloc = sv[0];
        #pragma unroll
        for (int i = 1; i < 16; ++i) mloc = fmaxf(mloc, sv[i]);
        mloc = fmaxf(mloc, __shfl_xor(mloc, 16));
        mloc = fmaxf(mloc, __shfl_xor(mloc, 32));

        const float mn = fmaxf(m, mloc);
        const float cc = __expf(m - mn);          // first tile: exp(-inf)=0
        float lsum = 0.f;
        #pragma unroll
        for (int i = 0; i < 16; ++i) {
            const float p = __expf(sv[i] - mn);   // masked -> 0
            sv[i] = p;
            lsum += p;
        }
        lsum += __shfl_xor(lsum, 16);
        lsum += __shfl_xor(lsum, 32);
        l = l * cc + lsum;
        m = mn;

        // P^T -> LDS (bf16), wave-private, layout P[q][key]
        #pragma unroll
        for (int kf = 0; kf < 4; ++kf) {
            u16x4 pk;
            #pragma unroll
            for (int r = 0; r < 4; ++r) pk[r] = f2bf(sv[kf * 4 + r]);
            *(u16x4*)&P[wave][col][kf * 16 + g * 4] = pk;
        }

        // rescale accumulator
        #pragma unroll
        for (int df = 0; df < 4; ++df)
            #pragma unroll
            for (int r = 0; r < 4; ++r) o[df][r] *= cc;

        // PV: O^T += V^T . P^T
        const bf16x8 pb0 = *(const bf16x8*)&P[wave][col][g * 8];
        const bf16x8 pb1 = *(const bf16x8*)&P[wave][col][32 + g * 8];
        #pragma unroll
        for (int df = 0; df < 4; ++df) {
            const u16* Vrow = Vbase + (((size_t)(df * 16 + col)) << 11) + k0;
            const bf16x8 va0 = *(const bf16x8*)(Vrow + g * 8);
            const bf16x8 va1 = *(const bf16x8*)(Vrow + 32 + g * 8);
            o[df] = MFMA16(va0, pb0, o[df]);
            o[df] = MFMA16(va1, pb1, o[df]);
        }
    }

    const float invl = 1.0f / l;
    u16* Orow = AOb + (size_t)(b * SEQ + q0 + col) * DIM + h * HDM;
    #pragma unroll
    for (int df = 0; df < 4; ++df) {
        u16x4 pk;
        #pragma unroll
        for (int r = 0; r < 4; ++r) pk[r] = f2bf(o[df][r] * invl);
        *(u16x4*)(Orow + df * 16 + g * 4) = pk;
    }
}

} // namespace

// ---------------------------------------------------------------------------
extern "C" void kernel_launch(void* const* d_in, const int* in_sizes, int n_in,
                              void* d_out, int out_size, void* d_ws, size_t ws_size,
                              hipStream_t stream)
{
    const float* x  = (const float*)d_in[0];
    const float* wq = (const float*)d_in[1];
    const float* wk = (const float*)d_in[2];
    const float* wv = (const float*)d_in[3];
    const float* wo = (const float*)d_in[4];
    const float* wb = (const float*)d_in[5];
    float* out = (float*)d_out;

    u16* ws = (u16*)d_ws;                      // 48 MB of bf16 scratch
    u16* xb  = ws;                             // 4M
    u16* wqb = ws + ((size_t)4 << 20);         // 1M each
    u16* wkb = ws + ((size_t)5 << 20);
    u16* wvb = ws + ((size_t)6 << 20);
    u16* wob = ws + ((size_t)7 << 20);
    u16* Qb  = ws + ((size_t)8 << 20);         // 4M
    u16* Kb  = ws + ((size_t)12 << 20);        // 4M
    u16* Vtb = ws + ((size_t)16 << 20);        // 4M
    u16* AOb = ws + ((size_t)20 << 20);        // 4M

    convert_bf16<<<dim3(512, 5), 256, 0, stream>>>(x, wq, wk, wv, wo, ws);
    gemm_qkv<<<dim3(8, 32, 3), 256, 0, stream>>>(xb, wqb, wkb, wvb, Qb, Kb, Vtb);
    attn_mfma<<<dim3(32, NHE, 2), 256, 0, stream>>>(Qb, Kb, Vtb, AOb);
    gemm_out<<<dim3(8, 32), 256, 0, stream>>>(AOb, wob, wb, out);
}

// Round 5
// 274.551 us; speedup vs baseline: 6.4248x; 1.4119x over previous
//
#include <hip/hip_runtime.h>
#include <math.h>
#include <stdint.h>

namespace {

typedef unsigned short u16;
typedef short    bf16x8 __attribute__((ext_vector_type(8)));   // 8 bf16 (4 VGPR)
typedef float    f32x4  __attribute__((ext_vector_type(4)));
typedef u16      u16x4  __attribute__((ext_vector_type(4)));
typedef u16      u16x8  __attribute__((ext_vector_type(8)));

constexpr int SEQ = 2048;
constexpr int DIM = 1024;
constexpr int NHE = 16;
constexpr int HDM = 64;

__device__ __forceinline__ u16 f2bf(float f) {   // RNE fp32 -> bf16
    uint32_t u = __float_as_uint(f);
    u += 0x7fffu + ((u >> 16) & 1u);
    return (u16)(u >> 16);
}

#define MFMA16(a, b, c) __builtin_amdgcn_mfma_f32_16x16x32_bf16((a), (b), (c), 0, 0, 0)

// async global -> LDS, 16 B per lane (wave-uniform base + lane*16)
__device__ __forceinline__ void gl_lds16(const void* g, void* l) {
    __builtin_amdgcn_global_load_lds(
        (const __attribute__((address_space(1))) void*)g,
        (__attribute__((address_space(3))) void*)l, 16, 0, 0);
}

// ---------------------------------------------------------------------------
// fp32 -> bf16 conversion for x and the 4 weight matrices.
// ---------------------------------------------------------------------------
__global__ __launch_bounds__(256)
void convert_bf16(const float* __restrict__ x,  const float* __restrict__ wq,
                  const float* __restrict__ wk, const float* __restrict__ wv,
                  const float* __restrict__ wo, u16* __restrict__ ws)
{
    const int id = blockIdx.y;
    const float* src;  u16* dst;  int n;
    if      (id == 0) { src = x;  dst = ws;                        n = 1 << 22; }
    else if (id == 1) { src = wq; dst = ws + ((size_t)4 << 20);    n = 1 << 20; }
    else if (id == 2) { src = wk; dst = ws + ((size_t)5 << 20);    n = 1 << 20; }
    else if (id == 3) { src = wv; dst = ws + ((size_t)6 << 20);    n = 1 << 20; }
    else              { src = wo; dst = ws + ((size_t)7 << 20);    n = 1 << 20; }

    const int stride = gridDim.x * 256 * 8;
    for (int i = (blockIdx.x * 256 + threadIdx.x) * 8; i < n; i += stride) {
        const float4 a = *(const float4*)(src + i);
        const float4 b = *(const float4*)(src + i + 4);
        u16x8 o;
        o[0] = f2bf(a.x); o[1] = f2bf(a.y); o[2] = f2bf(a.z); o[3] = f2bf(a.w);
        o[4] = f2bf(b.x); o[5] = f2bf(b.y); o[6] = f2bf(b.z); o[7] = f2bf(b.w);
        *(u16x8*)(dst + i) = o;
    }
}

// ---------------------------------------------------------------------------
// bf16 GEMM core (m97 structure): C[128x128] tile of A[M,1024] @ W[1024,1024]^T.
// 256 threads = 4 waves (2x2), wave tile 64x64 = 4x4 fragments of 16x16.
// Linear LDS [128][32], staged via global_load_lds width=16, 2 barriers/K-step.
// ---------------------------------------------------------------------------
__device__ __forceinline__ void gemm_core(
    const u16* __restrict__ A, const u16* __restrict__ W,
    int row0, int col0, u16* As, u16* Bs, f32x4 acc[4][4])
{
    const int tid  = threadIdx.x;
    const int lane = tid & 63;
    const int wave = tid >> 6;
    const int wm = wave >> 1, wn = wave & 1;
    const int col = lane & 15, g = lane >> 4;
    const int qr = lane >> 2, qk = (lane & 3) << 3;   // staging row/k within wave slab

    // issue 0 covers tile rows [wave*16, +16), issue 1 rows [64 + wave*16, +16)
    const u16* Arow0 = A + (size_t)(row0 + wave * 16 + qr) * DIM + qk;
    const u16* Arow1 = A + (size_t)(row0 + 64 + wave * 16 + qr) * DIM + qk;
    const u16* Wrow0 = W + (size_t)(col0 + wave * 16 + qr) * DIM + qk;
    const u16* Wrow1 = W + (size_t)(col0 + 64 + wave * 16 + qr) * DIM + qk;

    u16* lA0 = As + wave * 512 + lane * 8;
    u16* lA1 = As + 2048 + wave * 512 + lane * 8;
    u16* lB0 = Bs + wave * 512 + lane * 8;
    u16* lB1 = Bs + 2048 + wave * 512 + lane * 8;

    for (int kt = 0; kt < DIM; kt += 32) {
        __syncthreads();                  // previous tile's ds_reads done
        gl_lds16(Arow0 + kt, lA0);
        gl_lds16(Arow1 + kt, lA1);
        gl_lds16(Wrow0 + kt, lB0);
        gl_lds16(Wrow1 + kt, lB1);
        __syncthreads();                  // drains vmcnt -> LDS ready

        bf16x8 af[4], bfr[4];
        #pragma unroll
        for (int i = 0; i < 4; ++i)
            af[i] = *(const bf16x8*)(As + (wm * 64 + i * 16 + col) * 32 + g * 8);
        #pragma unroll
        for (int i = 0; i < 4; ++i)
            bfr[i] = *(const bf16x8*)(Bs + (wn * 64 + i * 16 + col) * 32 + g * 8);
        #pragma unroll
        for (int i = 0; i < 4; ++i)
            #pragma unroll
            for (int j = 0; j < 4; ++j)
                acc[i][j] = MFMA16(af[i], bfr[j], acc[i][j]);
    }
}

// ---------------------------------------------------------------------------
// QKV projections. z=0 -> Q, z=1 -> K (row-major [4096][1024] bf16);
// z=2 -> V written transposed per head: Vt[(b*16+h)*64 + d][s] (bf16).
// ---------------------------------------------------------------------------
__global__ __launch_bounds__(256)
void gemm_qkv(const u16* __restrict__ xb,  const u16* __restrict__ wqb,
              const u16* __restrict__ wkb, const u16* __restrict__ wvb,
              u16* __restrict__ Qb, u16* __restrict__ Kb, u16* __restrict__ Vtb)
{
    __shared__ u16 As[128 * 32];
    __shared__ u16 Bs[128 * 32];

    const int z = blockIdx.z;
    const u16* W = (z == 0) ? wqb : (z == 1) ? wkb : wvb;
    const int row0 = blockIdx.y * 128, col0 = blockIdx.x * 128;

    f32x4 acc[4][4];
    const f32x4 zero = {0.f, 0.f, 0.f, 0.f};
    #pragma unroll
    for (int i = 0; i < 4; ++i)
        #pragma unroll
        for (int j = 0; j < 4; ++j) acc[i][j] = zero;

    gemm_core(xb, W, row0, col0, As, Bs, acc);

    const int lane = threadIdx.x & 63, wave = threadIdx.x >> 6;
    const int wm = wave >> 1, wn = wave & 1;
    const int col = lane & 15, g = lane >> 4;

    if (z < 2) {
        u16* O = z ? Kb : Qb;
        #pragma unroll
        for (int i = 0; i < 4; ++i) {
            const int r_ = row0 + wm * 64 + i * 16 + g * 4;
            #pragma unroll
            for (int j = 0; j < 4; ++j) {
                const int c_ = col0 + wn * 64 + j * 16 + col;
                #pragma unroll
                for (int r = 0; r < 4; ++r)
                    O[(size_t)(r_ + r) * DIM + c_] = f2bf(acc[i][j][r]);
            }
        }
    } else {
        #pragma unroll
        for (int i = 0; i < 4; ++i) {
            const int r_ = row0 + wm * 64 + i * 16 + g * 4;   // 4-aligned
            const int b = r_ >> 11, s = r_ & 2047;
            #pragma unroll
            for (int j = 0; j < 4; ++j) {
                const int c_ = col0 + wn * 64 + j * 16 + col;
                const int h = c_ >> 6, d = c_ & 63;
                u16x4 pk;
                #pragma unroll
                for (int r = 0; r < 4; ++r) pk[r] = f2bf(acc[i][j][r]);
                *(u16x4*)(Vtb + (((size_t)(b * NHE + h) * HDM + d) << 11) + s) = pk;
            }
        }
    }
}

// ---------------------------------------------------------------------------
// Output projection: out = AO @ wo^T + bias (fp32 out).
// ---------------------------------------------------------------------------
__global__ __launch_bounds__(256)
void gemm_out(const u16* __restrict__ AOb, const u16* __restrict__ wob,
              const float* __restrict__ bias, float* __restrict__ out)
{
    __shared__ u16 As[128 * 32];
    __shared__ u16 Bs[128 * 32];

    const int row0 = blockIdx.y * 128, col0 = blockIdx.x * 128;
    f32x4 acc[4][4];
    const f32x4 zero = {0.f, 0.f, 0.f, 0.f};
    #pragma unroll
    for (int i = 0; i < 4; ++i)
        #pragma unroll
        for (int j = 0; j < 4; ++j) acc[i][j] = zero;

    gemm_core(AOb, wob, row0, col0, As, Bs, acc);

    const int lane = threadIdx.x & 63, wave = threadIdx.x >> 6;
    const int wm = wave >> 1, wn = wave & 1;
    const int col = lane & 15, g = lane >> 4;

    #pragma unroll
    for (int i = 0; i < 4; ++i) {
        const int r_ = row0 + wm * 64 + i * 16 + g * 4;
        #pragma unroll
        for (int j = 0; j < 4; ++j) {
            const int c_ = col0 + wn * 64 + j * 16 + col;
            const float bv = bias[c_];
            #pragma unroll
            for (int r = 0; r < 4; ++r)
                out[(size_t)(r_ + r) * DIM + c_] = acc[i][j][r] + bv;
        }
    }
}

// ---------------------------------------------------------------------------
// MFMA flash attention (causal), balanced + software-pipelined.
// grid=(16,16,2), 256 thr = 4 waves. Wave w processes q-fragment PAIR
// (f0 = bx*4+w, 127-f0): every wave does exactly 33 tile-iters (uniform).
// Per iter: V-frags loaded at top (fly under QK^T+softmax), next K-tile
// loaded right after QK^T (fly under softmax+PV). Two-buffer K unroll.
// Swapped QK^T (S^T = mfma(K,Q)); P via wave-private LDS; no __syncthreads.
// ---------------------------------------------------------------------------
__global__ __launch_bounds__(256, 2)
void attn_mfma(const u16* __restrict__ Qb, const u16* __restrict__ Kb,
               const u16* __restrict__ Vtb, u16* __restrict__ AOb)
{
    __shared__ u16 P[4][16][80];        // [wave][q][key 0..63, pad 80]

    const int tid = threadIdx.x, lane = tid & 63, wave = tid >> 6;
    const int col = lane & 15, g = lane >> 4;
    const int h = blockIdx.y, b = blockIdx.z;
    const int f0 = blockIdx.x * 4 + wave;    // 0..63
    const float scale = 0.125f;              // 1/sqrt(64)

    const u16* Kbase = Kb + (size_t)(b * SEQ) * DIM + h * HDM;
    const u16* Vbase = Vtb + (((size_t)(b * NHE + h) * HDM) << 11);

    #pragma unroll 1
    for (int fi = 0; fi < 2; ++fi) {
        const int f  = fi ? (127 - f0) : f0; // q-fragment index, 16 rows
        const int q0 = f * 16;
        const int nt = (f >> 2) + 1;         // causal k-tiles (64-wide)
        const int dt = f >> 2;               // diagonal tile index
        const int qg = q0 + col;             // this lane's q row

        const u16* Qrow = Qb + (size_t)(b * SEQ + qg) * DIM + h * HDM;
        const bf16x8 qf0 = *(const bf16x8*)(Qrow + g * 8);
        const bf16x8 qf1 = *(const bf16x8*)(Qrow + 32 + g * 8);

        float m = -INFINITY, l = 0.f;
        f32x4 o[4];
        const f32x4 zero = {0.f, 0.f, 0.f, 0.f};
        #pragma unroll
        for (int i = 0; i < 4; ++i) o[i] = zero;

        bf16x8 kA[8], kB[8];

        auto loadK = [&](bf16x8 (&kr)[8], int kt) {
            const int k0 = kt * 64;
            #pragma unroll
            for (int kf = 0; kf < 4; ++kf) {
                const u16* Krow = Kbase + (size_t)(k0 + kf * 16 + col) * DIM;
                kr[kf * 2]     = *(const bf16x8*)(Krow + g * 8);
                kr[kf * 2 + 1] = *(const bf16x8*)(Krow + 32 + g * 8);
            }
        };

        auto body = [&](bf16x8 (&kc)[8], bf16x8 (&kn)[8], int kt) {
            const int k0 = kt * 64;
            // V fragments: issue first, consumed last (PV)
            bf16x8 vr[8];
            #pragma unroll
            for (int df = 0; df < 4; ++df) {
                const u16* Vrow = Vbase + (((size_t)(df * 16 + col)) << 11) + k0;
                vr[df * 2]     = *(const bf16x8*)(Vrow + g * 8);
                vr[df * 2 + 1] = *(const bf16x8*)(Vrow + 32 + g * 8);
            }
            // S^T tile from current K regs
            f32x4 st[4];
            #pragma unroll
            for (int kf = 0; kf < 4; ++kf) {
                f32x4 z = zero;
                z = MFMA16(kc[kf * 2], qf0, z);
                z = MFMA16(kc[kf * 2 + 1], qf1, z);
                st[kf] = z;
            }
            // prefetch next K tile (flies under softmax + PV)
            if (kt + 1 < nt) loadK(kn, kt + 1);

            float sv[16];
            #pragma unroll
            for (int kf = 0; kf < 4; ++kf)
                #pragma unroll
                for (int r = 0; r < 4; ++r)
                    sv[kf * 4 + r] = st[kf][r] * scale;

            if (kt == dt) {                  // diagonal tile: causal mask
                #pragma unroll
                for (int kf = 0; kf < 4; ++kf)
                    #pragma unroll
                    for (int r = 0; r < 4; ++r)
                        if (k0 + kf * 16 + g * 4 + r > qg)
                            sv[kf * 4 + r] = -INFINITY;
            }

            float mloc = sv[0];
            #pragma unroll
            for (int i = 1; i < 16; ++i) mloc = fmaxf(mloc, sv[i]);
            mloc = fmaxf(mloc, __shfl_xor(mloc, 16));
            mloc = fmaxf(mloc, __shfl_xor(mloc, 32));

            const float mn = fmaxf(m, mloc);
            const float cc = __expf(m - mn);          // first tile: 0
            float lsum = 0.f;
            #pragma unroll
            for (int i = 0; i < 16; ++i) {
                const float p = __expf(sv[i] - mn);   // masked -> 0
                sv[i] = p;
                lsum += p;
            }
            lsum += __shfl_xor(lsum, 16);
            lsum += __shfl_xor(lsum, 32);
            l = l * cc + lsum;
            m = mn;

            // P^T -> wave-private LDS (bf16), layout P[q][key]
            #pragma unroll
            for (int kf = 0; kf < 4; ++kf) {
                u16x4 pk;
                #pragma unroll
                for (int r = 0; r < 4; ++r) pk[r] = f2bf(sv[kf * 4 + r]);
                *(u16x4*)&P[wave][col][kf * 16 + g * 4] = pk;
            }

            #pragma unroll
            for (int df = 0; df < 4; ++df)
                #pragma unroll
                for (int r = 0; r < 4; ++r) o[df][r] *= cc;

            const bf16x8 pb0 = *(const bf16x8*)&P[wave][col][g * 8];
            const bf16x8 pb1 = *(const bf16x8*)&P[wave][col][32 + g * 8];
            #pragma unroll
            for (int df = 0; df < 4; ++df) {
                o[df] = MFMA16(vr[df * 2],     pb0, o[df]);
                o[df] = MFMA16(vr[df * 2 + 1], pb1, o[df]);
            }
        };

        loadK(kA, 0);
        int kt = 0;
        for (;;) {
            body(kA, kB, kt); if (++kt == nt) break;
            body(kB, kA, kt); if (++kt == nt) break;
        }

        const float invl = 1.0f / l;
        u16* Orow = AOb + (size_t)(b * SEQ + qg) * DIM + h * HDM;
        #pragma unroll
        for (int df = 0; df < 4; ++df) {
            u16x4 pk;
            #pragma unroll
            for (int r = 0; r < 4; ++r) pk[r] = f2bf(o[df][r] * invl);
            *(u16x4*)(Orow + df * 16 + g * 4) = pk;
        }
    }
}

} // namespace

// ---------------------------------------------------------------------------
extern "C" void kernel_launch(void* const* d_in, const int* in_sizes, int n_in,
                              void* d_out, int out_size, void* d_ws, size_t ws_size,
                              hipStream_t stream)
{
    const float* x  = (const float*)d_in[0];
    const float* wq = (const float*)d_in[1];
    const float* wk = (const float*)d_in[2];
    const float* wv = (const float*)d_in[3];
    const float* wo = (const float*)d_in[4];
    const float* wb = (const float*)d_in[5];
    float* out = (float*)d_out;

    u16* ws = (u16*)d_ws;                      // 48 MB of bf16 scratch
    u16* xb  = ws;                             // 4M
    u16* wqb = ws + ((size_t)4 << 20);         // 1M each
    u16* wkb = ws + ((size_t)5 << 20);
    u16* wvb = ws + ((size_t)6 << 20);
    u16* wob = ws + ((size_t)7 << 20);
    u16* Qb  = ws + ((size_t)8 << 20);         // 4M
    u16* Kb  = ws + ((size_t)12 << 20);        // 4M
    u16* Vtb = ws + ((size_t)16 << 20);        // 4M
    u16* AOb = ws + ((size_t)20 << 20);        // 4M

    convert_bf16<<<dim3(512, 5), 256, 0, stream>>>(x, wq, wk, wv, wo, ws);
    gemm_qkv<<<dim3(8, 32, 3), 256, 0, stream>>>(xb, wqb, wkb, wvb, Qb, Kb, Vtb);
    attn_mfma<<<dim3(16, NHE, 2), 256, 0, stream>>>(Qb, Kb, Vtb, AOb);
    gemm_out<<<dim3(8, 32), 256, 0, stream>>>(AOb, wob, wb, out);
}